// Round 2
// baseline (513.773 us; speedup 1.0000x reference)
//
#include <hip/hip_runtime.h>
#include <hip/hip_bf16.h>

#define B_TOTAL 262144
#define NREG 32
#define BITW 64
#define KDIM 256

__device__ __forceinline__ float geluf(float x){
    return 0.5f * x * (1.0f + erff(x * 0.70710678118654752440f));
}

__device__ __forceinline__ float bf16_to_f(unsigned short u){
    unsigned int v = ((unsigned int)u) << 16;
    return __uint_as_float(v);
}

// round-to-nearest-even f32 -> bf16 bits (used only for LDS weight compression)
__device__ __forceinline__ unsigned short f_to_bf16(float f){
    unsigned int x = __float_as_uint(f);
    unsigned int lsb = (x >> 16) & 1u;
    x += 0x7fffu + lsb;
    return (unsigned short)(x >> 16);
}

// ---------------------------------------------------------------------------
// K1: attention table for the 32 possible indices.
// block = idx, 256 threads. Tiny: correctness over speed.
// ---------------------------------------------------------------------------
__global__ void __launch_bounds__(256) k_att_table(
    const float* __restrict__ qw1, const float* __restrict__ qb1,
    const float* __restrict__ qg1, const float* __restrict__ qbt1,
    const float* __restrict__ qw2, const float* __restrict__ qb2,
    const float* __restrict__ qg2, const float* __restrict__ qbt2,
    const float* __restrict__ qw3, const float* __restrict__ qb3,
    const float* __restrict__ keys, const float* __restrict__ temp_p,
    float* __restrict__ att_out)
{
    __shared__ float red[256];
    __shared__ float bc[2];
    __shared__ float h1s[128];
    __shared__ float h2s[256];
    __shared__ float qns[256];
    __shared__ float svs[32];
    const int idx = blockIdx.x;
    const int t = threadIdx.x;

    // layer 1: 5 -> 128
    float a1 = 0.f;
    if (t < 128){
        a1 = qb1[t];
        #pragma unroll
        for (int k = 0; k < 5; ++k){
            float bit = (float)((idx >> k) & 1);
            a1 += bit * qw1[k*128 + t];
        }
    }
    red[t] = (t < 128) ? a1 : 0.f;
    __syncthreads();
    if (t == 0){ float s = 0.f; for (int i = 0; i < 128; ++i) s += red[i]; bc[0] = s * (1.f/128.f); }
    __syncthreads();
    float m1 = bc[0];
    { float d = (t < 128) ? (a1 - m1) : 0.f; red[t] = d * d; }
    __syncthreads();
    if (t == 0){ float s = 0.f; for (int i = 0; i < 128; ++i) s += red[i]; bc[1] = s * (1.f/128.f); }
    __syncthreads();
    if (t < 128){
        float x = (a1 - m1) * rsqrtf(bc[1] + 1e-5f) * qg1[t] + qbt1[t];
        h1s[t] = geluf(x);
    }
    __syncthreads();

    // layer 2: 128 -> 256
    float a2 = qb2[t];
    for (int k = 0; k < 128; ++k) a2 += h1s[k] * qw2[k*256 + t];
    red[t] = a2;
    __syncthreads();
    if (t == 0){ float s = 0.f; for (int i = 0; i < 256; ++i) s += red[i]; bc[0] = s * (1.f/256.f); }
    __syncthreads();
    float m2 = bc[0];
    { float d = a2 - m2; red[t] = d * d; }
    __syncthreads();
    if (t == 0){ float s = 0.f; for (int i = 0; i < 256; ++i) s += red[i]; bc[1] = s * (1.f/256.f); }
    __syncthreads();
    { float x = (a2 - m2) * rsqrtf(bc[1] + 1e-5f) * qg2[t] + qbt2[t]; h2s[t] = geluf(x); }
    __syncthreads();

    // layer 3: 256 -> 256, then l2norm
    float a3 = qb3[t];
    for (int k = 0; k < 256; ++k) a3 += h2s[k] * qw3[k*256 + t];
    red[t] = a3 * a3;
    __syncthreads();
    if (t == 0){ float s = 0.f; for (int i = 0; i < 256; ++i) s += red[i]; bc[0] = fmaxf(sqrtf(s), 1e-12f); }
    __syncthreads();
    qns[t] = a3 / bc[0];
    __syncthreads();

    // similarities against l2-normalized keys
    if (t < 32){
        const float* kr = keys + t * 256;
        float dot = 0.f, ss = 0.f;
        for (int k = 0; k < 256; ++k){ float kv = kr[k]; dot += qns[k] * kv; ss += kv * kv; }
        svs[t] = dot / fmaxf(sqrtf(ss), 1e-12f);
    }
    __syncthreads();
    if (t < 32){
        float temp = fmaxf(fabsf(temp_p[0]), 0.01f);
        float inv = 1.f / temp;
        float mx = -1e30f;
        for (int i = 0; i < 32; ++i) mx = fmaxf(mx, svs[i]);
        float se = 0.f;
        for (int i = 0; i < 32; ++i) se += expf((svs[i] - mx) * inv);
        att_out[idx*32 + t] = expf((svs[t] - mx) * inv) / se;
    }
}

// ---------------------------------------------------------------------------
// K2: the heavy kernel. Per batch row: enc = gelu(LN(val@vw1+vb1))@vw2+vb2,
// accumulated into enc_sum[write_idx] plus a histogram of write_idx.
// 4 waves/block, each wave processes 4 rows at a time.
// lane owns hidden units j0=2*lane, j1=2*lane+1 in mm1, output dim d=lane in mm2.
// LDS: vw1 f32 (32KB) + vw2^T bf16 (16.5KB) + staging + block accumulators.
// ---------------------------------------------------------------------------
__global__ void __launch_bounds__(256) k_encsum(
    const float* __restrict__ wval, const int* __restrict__ widx,
    const float* __restrict__ vw1, const float* __restrict__ vb1,
    const float* __restrict__ vg1, const float* __restrict__ vbt1,
    const float* __restrict__ vw2, const float* __restrict__ vb2,
    float* __restrict__ g_encsum, float* __restrict__ g_cnt)
{
    __shared__ float s_w1[64*128];                // [k][j]
    __shared__ unsigned short s_w2t[64][132];     // [d][j] transposed, padded (8B aligned rows)
    __shared__ float s_val[4][64][4];             // per-wave [k][row]
    __shared__ float s_h[4][128][4];              // per-wave [j][row]
    __shared__ float s_acc[NREG*BITW];
    __shared__ float s_cnt[NREG];

    const int t = threadIdx.x;
    const int lane = t & 63;
    const int wid = t >> 6;

    for (int e = t; e < 64*128; e += 256) s_w1[e] = vw1[e];
    for (int e = t; e < 128*64; e += 256){
        int j = e >> 6, d = e & 63;
        s_w2t[d][j] = f_to_bf16(vw2[e]);
    }
    for (int e = t; e < NREG*BITW; e += 256) s_acc[e] = 0.f;
    if (t < NREG) s_cnt[t] = 0.f;
    __syncthreads();

    const float2 g12  = ((const float2*)vg1 )[lane];
    const float2 bt12 = ((const float2*)vbt1)[lane];
    const float2 b12  = ((const float2*)vb1 )[lane];
    const float  b2v  = vb2[lane];

    const int gw = blockIdx.x * 4 + wid;   // 8192 waves * 32 rows = 262144

    for (int it = 0; it < 8; ++it){
        const int r0 = gw * 32 + it * 4;
        float vv[4]; int wi[4];
        #pragma unroll
        for (int i = 0; i < 4; ++i){
            wi[i] = widx[r0 + i];
            float x = wval[(size_t)(r0 + i) * 64 + lane];
            vv[i] = (wi[i] == 31) ? 0.f : x;
        }
        *(float4*)(&s_val[wid][lane][0]) = make_float4(vv[0], vv[1], vv[2], vv[3]);

        // mm1: h[j] = b1[j] + sum_k val[k]*w1[k][j]
        float h0[4], h1[4];
        #pragma unroll
        for (int i = 0; i < 4; ++i){ h0[i] = b12.x; h1[i] = b12.y; }
        #pragma unroll 4
        for (int k = 0; k < 64; ++k){
            float4 vk = *(const float4*)(&s_val[wid][k][0]);
            float2 w  = *(const float2*)(&s_w1[k*128 + 2*lane]);
            float va[4] = {vk.x, vk.y, vk.z, vk.w};
            #pragma unroll
            for (int i = 0; i < 4; ++i){
                h0[i] = fmaf(va[i], w.x, h0[i]);
                h1[i] = fmaf(va[i], w.y, h1[i]);
            }
        }

        // LN over 128 (wave allreduce) + gelu
        float hg0[4], hg1[4];
        #pragma unroll
        for (int i = 0; i < 4; ++i){
            float s = h0[i] + h1[i];
            #pragma unroll
            for (int off = 1; off < 64; off <<= 1) s += __shfl_xor(s, off, 64);
            float mean = s * (1.f/128.f);
            float d0 = h0[i] - mean, d1 = h1[i] - mean;
            float v = d0*d0 + d1*d1;
            #pragma unroll
            for (int off = 1; off < 64; off <<= 1) v += __shfl_xor(v, off, 64);
            float rstd = rsqrtf(v * (1.f/128.f) + 1e-5f);
            hg0[i] = geluf(d0 * rstd * g12.x + bt12.x);
            hg1[i] = geluf(d1 * rstd * g12.y + bt12.y);
        }
        *(float4*)(&s_h[wid][2*lane    ][0]) = make_float4(hg0[0], hg0[1], hg0[2], hg0[3]);
        *(float4*)(&s_h[wid][2*lane + 1][0]) = make_float4(hg1[0], hg1[1], hg1[2], hg1[3]);

        // mm2: enc[d] = b2[d] + sum_j h[j]*w2[j][d],  d = lane
        float acc[4];
        #pragma unroll
        for (int i = 0; i < 4; ++i) acc[i] = b2v;
        #pragma unroll 2
        for (int j = 0; j < 128; j += 4){
            ushort4 wr = *(const ushort4*)(&s_w2t[lane][j]);
            float w0 = bf16_to_f(wr.x), w1f = bf16_to_f(wr.y);
            float w2f = bf16_to_f(wr.z), w3f = bf16_to_f(wr.w);
            float4 hA = *(const float4*)(&s_h[wid][j+0][0]);
            float4 hB = *(const float4*)(&s_h[wid][j+1][0]);
            float4 hC = *(const float4*)(&s_h[wid][j+2][0]);
            float4 hD = *(const float4*)(&s_h[wid][j+3][0]);
            float a4[4] = {hA.x, hA.y, hA.z, hA.w};
            float b4[4] = {hB.x, hB.y, hB.z, hB.w};
            float c4[4] = {hC.x, hC.y, hC.z, hC.w};
            float d4[4] = {hD.x, hD.y, hD.z, hD.w};
            #pragma unroll
            for (int i = 0; i < 4; ++i){
                acc[i] = fmaf(a4[i], w0, acc[i]);
                acc[i] = fmaf(b4[i], w1f, acc[i]);
                acc[i] = fmaf(c4[i], w2f, acc[i]);
                acc[i] = fmaf(d4[i], w3f, acc[i]);
            }
        }

        #pragma unroll
        for (int i = 0; i < 4; ++i) atomicAdd(&s_acc[wi[i]*64 + lane], acc[i]);
        if (lane == 0){
            #pragma unroll
            for (int i = 0; i < 4; ++i) atomicAdd(&s_cnt[wi[i]], 1.0f);
        }
    }
    __syncthreads();
    for (int e = t; e < NREG*BITW; e += 256) atomicAdd(&g_encsum[e], s_acc[e]);
    if (t < NREG) atomicAdd(&g_cnt[t], s_cnt[t]);
}

// ---------------------------------------------------------------------------
// K3: combine -> new_regs (fp32, at d_out tail) and rv_table = att @ new_regs
// ---------------------------------------------------------------------------
__global__ void __launch_bounds__(256) k_combine(
    const float* __restrict__ att, const float* __restrict__ encsum,
    const float* __restrict__ cnt, const float* __restrict__ regv,
    const float* __restrict__ wstr_p, float* __restrict__ rv_table,
    float* __restrict__ out_regs)
{
    __shared__ float s_att[NREG*NREG];
    __shared__ float s_am[NREG];
    __shared__ float s_nr[NREG*BITW];
    const int t = threadIdx.x;
    for (int e = t; e < NREG*NREG; e += 256) s_att[e] = att[e];
    __syncthreads();
    if (t < NREG){
        float s = 0.f;
        for (int i = 0; i < NREG; ++i) s += cnt[i] * s_att[i*NREG + t];
        s_am[t] = s * (1.f / (float)B_TOTAL);
    }
    __syncthreads();
    const float s = 1.f / (1.f + expf(-wstr_p[0]));
    for (int e = t; e < NREG*BITW; e += 256){
        int r = e >> 6, d = e & 63;
        float acc = 0.f;
        for (int i = 0; i < NREG; ++i) acc += s_att[i*NREG + r] * encsum[i*64 + d];
        float nr = (1.f - s * s_am[r]) * regv[e] + (s / (float)B_TOTAL) * acc;
        s_nr[e] = nr;
        out_regs[e] = nr;
    }
    __syncthreads();
    for (int e = t; e < NREG*BITW; e += 256){
        int i = e >> 6, d = e & 63;
        float acc = 0.f;
        for (int r = 0; r < NREG; ++r) acc += s_att[i*NREG + r] * s_nr[r*64 + d];
        rv_table[e] = (i == 31) ? 0.f : acc;
    }
}

// ---------------------------------------------------------------------------
// K4: read_value[b] = rv_table[read_idx[b]]  (fp32 out, float4 stores)
// ---------------------------------------------------------------------------
__global__ void __launch_bounds__(256) k_read(
    const int* __restrict__ ridx, const float* __restrict__ rv_table,
    float* __restrict__ out)
{
    __shared__ float s_rv[NREG*BITW];
    const int t = threadIdx.x;
    for (int e = t; e < NREG*BITW; e += 256) s_rv[e] = rv_table[e];
    __syncthreads();
    const int nq = B_TOTAL * 16;                 // 4 dims per quad
    for (int q = blockIdx.x * 256 + t; q < nq; q += gridDim.x * 256){
        int row = q >> 4;
        int sub = (q & 15) << 2;
        int ri = ridx[row];
        const float4 p = *(const float4*)(&s_rv[ri*64 + sub]);
        *(float4*)(out + (size_t)q * 4) = p;
    }
}

extern "C" void kernel_launch(void* const* d_in, const int* in_sizes, int n_in,
                              void* d_out, int out_size, void* d_ws, size_t ws_size,
                              hipStream_t stream)
{
    (void)in_sizes; (void)n_in; (void)out_size; (void)ws_size;
    const int*   widx = (const int*)  d_in[0];
    const float* wval = (const float*)d_in[1];
    const int*   ridx = (const int*)  d_in[2];
    const float* regv = (const float*)d_in[3];
    const float* keys = (const float*)d_in[4];
    const float* qw1  = (const float*)d_in[5];
    const float* qb1  = (const float*)d_in[6];
    const float* qg1  = (const float*)d_in[7];
    const float* qbt1 = (const float*)d_in[8];
    const float* qw2  = (const float*)d_in[9];
    const float* qb2  = (const float*)d_in[10];
    const float* qg2  = (const float*)d_in[11];
    const float* qbt2 = (const float*)d_in[12];
    const float* qw3  = (const float*)d_in[13];
    const float* qb3  = (const float*)d_in[14];
    const float* vw1  = (const float*)d_in[15];
    const float* vb1  = (const float*)d_in[16];
    const float* vg1  = (const float*)d_in[17];
    const float* vbt1 = (const float*)d_in[18];
    const float* vw2  = (const float*)d_in[19];
    const float* vb2  = (const float*)d_in[20];
    const float* temp = (const float*)d_in[21];
    const float* wstr = (const float*)d_in[22];

    float* ws     = (float*)d_ws;
    float* att    = ws;            // 1024 floats
    float* encsum = ws + 1024;     // 2048 floats
    float* cnt    = ws + 3072;     // 32 floats
    float* rvt    = ws + 3104;     // 2048 floats
    float* out    = (float*)d_out;

    hipMemsetAsync(encsum, 0, (2048 + 32) * sizeof(float), stream);
    k_att_table<<<32, 256, 0, stream>>>(qw1,qb1,qg1,qbt1,qw2,qb2,qg2,qbt2,qw3,qb3,keys,temp,att);
    k_encsum  <<<2048, 256, 0, stream>>>(wval,widx,vw1,vb1,vg1,vbt1,vw2,vb2,encsum,cnt);
    k_combine <<<1, 256, 0, stream>>>(att,encsum,cnt,regv,wstr,rvt, out + (size_t)B_TOTAL*64);
    k_read    <<<2048, 256, 0, stream>>>(ridx, rvt, out);
}

// Round 4
// 312.146 us; speedup vs baseline: 1.6459x; 1.6459x over previous
//
#include <hip/hip_runtime.h>
#include <hip/hip_bf16.h>
#include <math.h>

#define B_TOTAL 262144
#define NREG 32
#define BITW 64
#define NSLICE 16
#define SLICE_STRIDE (NREG*128 + NREG)   // 4128 floats per slice (HGS + cnt)

typedef float  f32x16 __attribute__((ext_vector_type(16)));
typedef short  short8 __attribute__((ext_vector_type(8)));
typedef int    i32x4  __attribute__((ext_vector_type(4)));

union FR { i32x4 w; short8 h; };

// v_cvt_pk_bf16_f32: dst.lo16 = bf16(a), dst.hi16 = bf16(b)  (RNE)
__device__ __forceinline__ unsigned pk_bf16(float a, float b){
    unsigned r;
    asm("v_cvt_pk_bf16_f32 %0, %1, %2" : "=v"(r) : "v"(a), "v"(b));
    return r;
}

// exact-erf gelu (used on the tiny att path only)
__device__ __forceinline__ float geluf(float x){
    return 0.5f * x * (1.0f + erff(x * 0.70710678118654752440f));
}

// tanh-form gelu: |err| < ~1.5e-3 abs, damped to ~1e-5 in outputs
__device__ __forceinline__ float gelu_fast(float x){
    float x2 = x*x;
    float t1 = fmaf(x2, 0.044715f, 1.0f);
    float z2 = x * t1 * 1.5957691216057308f;     // 2*sqrt(2/pi)
    float e  = __expf(z2);
    float r  = __builtin_amdgcn_rcpf(e + 1.0f);
    return x - x*r;                               // x*(1 - 1/(e^{2z}+1)) = 0.5x(1+tanh z)
}

// ---------------------------------------------------------------------------
// Fused kernel: blocks 0..31 compute the 32-row attention table;
// blocks 32..543 run the MFMA enc pipeline accumulating HGS[wi][j] and counts.
// ---------------------------------------------------------------------------
__global__ void __launch_bounds__(256, 2) k_fused(
    const float* __restrict__ wval, const int* __restrict__ widx,
    const float* __restrict__ vw1, const float* __restrict__ vb1,
    const float* __restrict__ vg1, const float* __restrict__ vbt1,
    const float* __restrict__ qw1, const float* __restrict__ qb1,
    const float* __restrict__ qg1, const float* __restrict__ qbt1,
    const float* __restrict__ qw2, const float* __restrict__ qb2,
    const float* __restrict__ qg2, const float* __restrict__ qbt2,
    const float* __restrict__ qw3, const float* __restrict__ qb3,
    const float* __restrict__ keys, const float* __restrict__ temp_p,
    float* __restrict__ att_out, float* __restrict__ hgs_g)
{
    __shared__ __align__(16) unsigned s_w1p[16*64*4];  // 16 frags x 64 lanes x 4 words
    __shared__ float s_hgs[NREG*128];
    __shared__ float s_cnt[NREG];
    __shared__ float red8[4];
    __shared__ float h1s[128];
    __shared__ float h2s[256];
    __shared__ float qns[256];
    __shared__ float svs[32];

    const int t    = threadIdx.x;
    const int lane = t & 63;
    const int wid  = t >> 6;
    const int l31  = lane & 31;
    const int lh   = lane >> 5;

    if (blockIdx.x < 32){
        // ---------------- attention table path ----------------
        const int idx = blockIdx.x;
        auto blksum = [&](float v)->float{
            #pragma unroll
            for (int o = 32; o >= 1; o >>= 1) v += __shfl_xor(v, o, 64);
            if (lane == 0) red8[wid] = v;
            __syncthreads();
            float r = red8[0] + red8[1] + red8[2] + red8[3];
            __syncthreads();
            return r;
        };

        float a1 = 0.f;
        if (t < 128){
            a1 = qb1[t];
            #pragma unroll
            for (int k = 0; k < 5; ++k)
                a1 += (float)((idx >> k) & 1) * qw1[k*128 + t];
        }
        float m1 = blksum(t < 128 ? a1 : 0.f) * (1.f/128.f);
        float d1 = (t < 128) ? (a1 - m1) : 0.f;
        float v1 = blksum(d1*d1) * (1.f/128.f);
        if (t < 128) h1s[t] = geluf(d1 * rsqrtf(v1 + 1e-5f) * qg1[t] + qbt1[t]);
        __syncthreads();

        float a2 = qb2[t];
        for (int k = 0; k < 128; ++k) a2 += h1s[k] * qw2[k*256 + t];
        float m2 = blksum(a2) * (1.f/256.f);
        float d2 = a2 - m2;
        float v2 = blksum(d2*d2) * (1.f/256.f);
        h2s[t] = geluf(d2 * rsqrtf(v2 + 1e-5f) * qg2[t] + qbt2[t]);
        __syncthreads();

        float a3 = qb3[t];
        for (int k = 0; k < 256; ++k) a3 += h2s[k] * qw3[k*256 + t];
        float nrm = blksum(a3*a3);
        qns[t] = a3 / fmaxf(sqrtf(nrm), 1e-12f);
        __syncthreads();

        if (t < 32){
            const float* kr = keys + t * 256;
            float dot = 0.f, ss = 0.f;
            for (int k = 0; k < 256; ++k){ float kv = kr[k]; dot += qns[k]*kv; ss += kv*kv; }
            svs[t] = dot / fmaxf(sqrtf(ss), 1e-12f);
        }
        __syncthreads();
        if (t < 32){
            float temp = fmaxf(fabsf(temp_p[0]), 0.01f);
            float inv = 1.f / temp;
            float mx = -1e30f;
            for (int i = 0; i < 32; ++i) mx = fmaxf(mx, svs[i]);
            float se = 0.f;
            for (int i = 0; i < 32; ++i) se += expf((svs[i] - mx) * inv);
            att_out[idx*32 + t] = expf((svs[t] - mx) * inv) / se;
        }
        return;
    }

    // ---------------- enc/HGS path ----------------
    const int eb = blockIdx.x - 32;          // 0..511, 512 rows per block

    // Build packed w1 fragments in LDS: frag f = ks*4+jt, per lane 4 u32 (8 bf16).
    for (int e = t; e < 16*64*4; e += 256){
        int wd  = e & 3;
        int lam = (e >> 2) & 63;
        int f   = e >> 8;
        int ks  = f >> 2, jt = f & 3;
        int k0  = ks*16 + (lam >> 5)*8 + wd*2;
        int j   = jt*32 + (lam & 31);
        s_w1p[e] = pk_bf16(vw1[k0*128 + j], vw1[(k0+1)*128 + j]);
    }
    for (int e = t; e < NREG*128; e += 256) s_hgs[e] = 0.f;
    if (t < NREG) s_cnt[t] = 0.f;
    __syncthreads();

    float b1v[4], gv[4], btv[4];
    #pragma unroll
    for (int jt = 0; jt < 4; ++jt){
        b1v[jt] = vb1 [jt*32 + l31];
        gv [jt] = vg1 [jt*32 + l31];
        btv[jt] = vbt1[jt*32 + l31];
    }
    FR ones;
    #pragma unroll
    for (int w = 0; w < 4; ++w) ones.w[w] = 0x3F803F80;

    f32x16 hgs[4], cntc;
    #pragma unroll
    for (int nt = 0; nt < 4; ++nt)
        #pragma unroll
        for (int e = 0; e < 16; ++e) hgs[nt][e] = 0.f;
    #pragma unroll
    for (int e = 0; e < 16; ++e) cntc[e] = 0.f;

    const long rowbase = (long)eb*512 + (long)wid*128;

    float4 rv[8]; int wivn;
    {
        const float* rp = wval + (size_t)(rowbase + l31)*64 + lh*8;
        #pragma unroll
        for (int ks = 0; ks < 4; ++ks){
            rv[2*ks  ] = *(const float4*)(rp + ks*16);
            rv[2*ks+1] = *(const float4*)(rp + ks*16 + 4);
        }
        wivn = widx[rowbase + l31];
    }

    #pragma unroll 1
    for (int g = 0; g < 4; ++g){
        const int cur_wiv = wivn;
        const float msk = (cur_wiv == 31) ? 0.f : 1.f;

        FR va[4];
        #pragma unroll
        for (int ks = 0; ks < 4; ++ks){
            float a0 = rv[2*ks].x*msk,  a1 = rv[2*ks].y*msk;
            float a2 = rv[2*ks].z*msk,  a3 = rv[2*ks].w*msk;
            float a4 = rv[2*ks+1].x*msk, a5 = rv[2*ks+1].y*msk;
            float a6 = rv[2*ks+1].z*msk, a7 = rv[2*ks+1].w*msk;
            va[ks].w[0] = (int)pk_bf16(a0, a1);
            va[ks].w[1] = (int)pk_bf16(a2, a3);
            va[ks].w[2] = (int)pk_bf16(a4, a5);
            va[ks].w[3] = (int)pk_bf16(a6, a7);
        }
        if (g < 3){  // prefetch next group
            const float* rp = wval + (size_t)(rowbase + (g+1)*32 + l31)*64 + lh*8;
            #pragma unroll
            for (int ks = 0; ks < 4; ++ks){
                rv[2*ks  ] = *(const float4*)(rp + ks*16);
                rv[2*ks+1] = *(const float4*)(rp + ks*16 + 4);
            }
            wivn = widx[rowbase + (g+1)*32 + l31];
        }

        // mm1: D1[b][j] = val @ w1  (+ b1 via accumulator init)
        f32x16 C1[4];
        #pragma unroll
        for (int jt = 0; jt < 4; ++jt)
            #pragma unroll
            for (int e = 0; e < 16; ++e) C1[jt][e] = b1v[jt];
        #pragma unroll
        for (int ks = 0; ks < 4; ++ks){
            FR bw[4];
            #pragma unroll
            for (int jt = 0; jt < 4; ++jt)
                bw[jt].w = *(const i32x4*)&s_w1p[((ks*4 + jt)*64 + lane)*4];
            #pragma unroll
            for (int jt = 0; jt < 4; ++jt)
                C1[jt] = __builtin_amdgcn_mfma_f32_32x32x16_bf16(va[ks].h, bw[jt].h, C1[jt], 0, 0, 0);
        }

        // LayerNorm over j (lanes): jt-collapse + 5-step butterfly per reg
        f32x16 sv, qv;
        #pragma unroll
        for (int e = 0; e < 16; ++e){
            float x0 = C1[0][e], x1 = C1[1][e], x2 = C1[2][e], x3 = C1[3][e];
            sv[e] = (x0 + x1) + (x2 + x3);
            qv[e] = fmaf(x0,x0, fmaf(x1,x1, fmaf(x2,x2, x3*x3)));
        }
        #pragma unroll
        for (int o = 1; o <= 16; o <<= 1){
            #pragma unroll
            for (int e = 0; e < 16; ++e) sv[e] += __shfl_xor(sv[e], o, 64);
            #pragma unroll
            for (int e = 0; e < 16; ++e) qv[e] += __shfl_xor(qv[e], o, 64);
        }
        f32x16 mn, rs;
        #pragma unroll
        for (int e = 0; e < 16; ++e){
            float m  = sv[e] * (1.f/128.f);
            float va_= qv[e] * (1.f/128.f) - m*m;
            mn[e] = m;
            rs[e] = rsqrtf(va_ + 1e-5f);
        }
        #pragma unroll
        for (int jt = 0; jt < 4; ++jt)
            #pragma unroll
            for (int e = 0; e < 16; ++e){
                float y = fmaf((C1[jt][e] - mn[e]) * rs[e], gv[jt], btv[jt]);
                C1[jt][e] = gelu_fast(y);
            }

        // HGS[wi][j] += onehot(wi)^T @ hg ; cnt += onehot^T @ ones
        #pragma unroll
        for (int ks2 = 0; ks2 < 2; ++ks2){
            FR oh;
            #pragma unroll
            for (int w = 0; w < 4; ++w){
                int b0 = ks2*16 + lh*8 + 2*w;
                int wa = __shfl(cur_wiv, b0,     64);
                int wb = __shfl(cur_wiv, b0 + 1, 64);
                oh.w[w] = (int)((wa == l31 ? 0x3F80u : 0u) | (wb == l31 ? 0x3F800000u : 0u));
            }
            cntc = __builtin_amdgcn_mfma_f32_32x32x16_bf16(oh.h, ones.h, cntc, 0, 0, 0);
            const int rb = ks2*8;
            #pragma unroll
            for (int nt = 0; nt < 4; ++nt){
                int P0 = (int)pk_bf16(C1[nt][rb+0], C1[nt][rb+1]);
                int P1 = (int)pk_bf16(C1[nt][rb+2], C1[nt][rb+3]);
                int Q0 = (int)pk_bf16(C1[nt][rb+4], C1[nt][rb+5]);
                int Q1 = (int)pk_bf16(C1[nt][rb+6], C1[nt][rb+7]);
                int sp0 = __shfl_xor(P0, 32, 64);
                int sq0 = __shfl_xor(Q0, 32, 64);
                int sp1 = __shfl_xor(P1, 32, 64);
                int sq1 = __shfl_xor(Q1, 32, 64);
                FR bf;
                bf.w[0] = lh ? sq0 : P0;
                bf.w[1] = lh ? sq1 : P1;
                bf.w[2] = lh ? Q0  : sp0;
                bf.w[3] = lh ? Q1  : sp1;
                hgs[nt] = __builtin_amdgcn_mfma_f32_32x32x16_bf16(oh.h, bf.h, hgs[nt], 0, 0, 0);
            }
        }
    }

    // block-level reduce: LDS atomics (bank-clean: addr % 32 == l31)
    #pragma unroll
    for (int nt = 0; nt < 4; ++nt)
        #pragma unroll
        for (int e = 0; e < 16; ++e){
            int m = (e & 3) + 8*(e >> 2) + 4*lh;
            atomicAdd(&s_hgs[m*128 + nt*32 + l31], hgs[nt][e]);
        }
    if (l31 == 0){
        #pragma unroll
        for (int e = 0; e < 16; ++e){
            int m = (e & 3) + 8*(e >> 2) + 4*lh;
            atomicAdd(&s_cnt[m], cntc[e]);
        }
    }
    __syncthreads();

    float* dst = hgs_g + (size_t)(eb & (NSLICE-1)) * SLICE_STRIDE;
    for (int e = t; e < NREG*128; e += 256) atomicAdd(&dst[e], s_hgs[e]);
    if (t < NREG) atomicAdd(&dst[NREG*128 + t], s_cnt[t]);
}

// ---------------------------------------------------------------------------
// Combine: reduce slices, encsum = HGS@w2 + cnt*b2, new_regs, rv_table.
// ---------------------------------------------------------------------------
__global__ void __launch_bounds__(256) k_combine(
    const float* __restrict__ att, const float* __restrict__ hgs_g,
    const float* __restrict__ regv, const float* __restrict__ vw2,
    const float* __restrict__ vb2, const float* __restrict__ wstr_p,
    float* __restrict__ rv_table, float* __restrict__ out_regs)
{
    __shared__ float s_hgs[NREG*128];
    __shared__ float s_cnt[NREG];
    __shared__ float s_att[NREG*NREG];
    __shared__ float s_enc[NREG*BITW];
    __shared__ float s_am[NREG];
    __shared__ float s_nr[NREG*BITW];
    const int t = threadIdx.x;

    for (int e = t; e < NREG*128; e += 256){
        float s = 0.f;
        for (int sl = 0; sl < NSLICE; ++sl) s += hgs_g[sl*SLICE_STRIDE + e];
        s_hgs[e] = s;
    }
    if (t < NREG){
        float s = 0.f;
        for (int sl = 0; sl < NSLICE; ++sl) s += hgs_g[sl*SLICE_STRIDE + NREG*128 + t];
        s_cnt[t] = s;
    }
    for (int e = t; e < NREG*NREG; e += 256) s_att[e] = att[e];
    __syncthreads();

    {   // encsum[i][d] = HGS[i]@w2[:,d] + cnt[i]*b2[d]
        int d = t & 63, i0 = t >> 6;
        for (int i = i0; i < NREG; i += 4){
            float acc = s_cnt[i] * vb2[d];
            for (int j = 0; j < 128; ++j)
                acc = fmaf(s_hgs[i*128 + j], vw2[j*64 + d], acc);
            s_enc[i*64 + d] = acc;
        }
    }
    if (t < NREG){
        float s = 0.f;
        for (int i = 0; i < NREG; ++i) s += s_cnt[i] * s_att[i*NREG + t];
        s_am[t] = s * (1.f / (float)B_TOTAL);
    }
    __syncthreads();

    const float s = 1.f / (1.f + expf(-wstr_p[0]));
    for (int e = t; e < NREG*BITW; e += 256){
        int r = e >> 6, d = e & 63;
        float acc = 0.f;
        for (int i = 0; i < NREG; ++i) acc = fmaf(s_att[i*NREG + r], s_enc[i*64 + d], acc);
        float nr = (1.f - s*s_am[r]) * regv[e] + (s / (float)B_TOTAL) * acc;
        s_nr[e] = nr;
        out_regs[e] = nr;
    }
    __syncthreads();
    for (int e = t; e < NREG*BITW; e += 256){
        int i = e >> 6, d = e & 63;
        float acc = 0.f;
        for (int r = 0; r < NREG; ++r) acc = fmaf(s_att[i*NREG + r], s_nr[r*64 + d], acc);
        rv_table[e] = (i == 31) ? 0.f : acc;
    }
}

// ---------------------------------------------------------------------------
// Read: read_value[b] = rv_table[read_idx[b]]  (float4 stores)
// ---------------------------------------------------------------------------
__global__ void __launch_bounds__(256) k_read(
    const int* __restrict__ ridx, const float* __restrict__ rv_table,
    float* __restrict__ out)
{
    __shared__ float s_rv[NREG*BITW];
    const int t = threadIdx.x;
    for (int e = t; e < NREG*BITW; e += 256) s_rv[e] = rv_table[e];
    __syncthreads();
    const int nq = B_TOTAL * 16;
    for (int q = blockIdx.x * 256 + t; q < nq; q += gridDim.x * 256){
        int row = q >> 4;
        int sub = (q & 15) << 2;
        int ri = ridx[row];
        *(float4*)(out + (size_t)q * 4) = *(const float4*)(&s_rv[ri*64 + sub]);
    }
}

extern "C" void kernel_launch(void* const* d_in, const int* in_sizes, int n_in,
                              void* d_out, int out_size, void* d_ws, size_t ws_size,
                              hipStream_t stream)
{
    (void)in_sizes; (void)n_in; (void)out_size; (void)ws_size;
    const int*   widx = (const int*)  d_in[0];
    const float* wval = (const float*)d_in[1];
    const int*   ridx = (const int*)  d_in[2];
    const float* regv = (const float*)d_in[3];
    const float* keys = (const float*)d_in[4];
    const float* qw1  = (const float*)d_in[5];
    const float* qb1  = (const float*)d_in[6];
    const float* qg1  = (const float*)d_in[7];
    const float* qbt1 = (const float*)d_in[8];
    const float* qw2  = (const float*)d_in[9];
    const float* qb2  = (const float*)d_in[10];
    const float* qg2  = (const float*)d_in[11];
    const float* qbt2 = (const float*)d_in[12];
    const float* qw3  = (const float*)d_in[13];
    const float* qb3  = (const float*)d_in[14];
    const float* vw1  = (const float*)d_in[15];
    const float* vb1  = (const float*)d_in[16];
    const float* vg1  = (const float*)d_in[17];
    const float* vbt1 = (const float*)d_in[18];
    const float* vw2  = (const float*)d_in[19];
    const float* vb2  = (const float*)d_in[20];
    const float* temp = (const float*)d_in[21];
    const float* wstr = (const float*)d_in[22];

    float* ws    = (float*)d_ws;
    float* att   = ws;                               // 1024
    float* hgs_g = ws + 1024;                        // 16 * 4128
    float* rvt   = ws + 1024 + NSLICE*SLICE_STRIDE;  // 2048
    float* out   = (float*)d_out;

    hipMemsetAsync(hgs_g, 0, (size_t)NSLICE*SLICE_STRIDE*sizeof(float), stream);
    k_fused  <<<544, 256, 0, stream>>>(wval, widx, vw1, vb1, vg1, vbt1,
                                       qw1,qb1,qg1,qbt1,qw2,qb2,qg2,qbt2,qw3,qb3,
                                       keys, temp, att, hgs_g);
    k_combine<<<1, 256, 0, stream>>>(att, hgs_g, regv, vw2, vb2, wstr,
                                     rvt, out + (size_t)B_TOTAL*64);
    k_read   <<<2048, 256, 0, stream>>>(ridx, rvt, out);
}